// Round 3
// 1132.099 us; speedup vs baseline: 1.1185x; 1.1185x over previous
//
#include <hip/hip_runtime.h>
#include <hip/hip_bf16.h>

#define T_ 1024
#define D_ 1024
#define H_ 16
#define KV_ 4
#define DH_ 64
#define E_ 8
#define TOPK_ 2
#define F_ 512
#define FS_ 2048
#define L_ 2

typedef unsigned int uint32;
typedef __attribute__((ext_vector_type(8))) short short8;
typedef __attribute__((ext_vector_type(4))) short short4v;
typedef __attribute__((ext_vector_type(4))) float f32x4;

__device__ __forceinline__ short f2bf(float f){   // RNE fp32 -> bf16 bits
  uint32 u = __float_as_uint(f);
  return (short)((u + 0x7fffu + ((u >> 16) & 1u)) >> 16);
}
__device__ __forceinline__ float bf2f(short s){
  return __uint_as_float(((uint32)(unsigned short)s) << 16);
}

__device__ __forceinline__ void split8(const float* src, short8& h8, short8& l8){
  #pragma unroll
  for (int j = 0; j < 8; j++){
    short hi = f2bf(src[j]);
    h8[j] = hi;
    l8[j] = f2bf(src[j] - bf2f(hi));
  }
}

// ---------------- embedding gather + zero residual ----------------
__global__ void k_embed(const int* __restrict__ ids, const float* __restrict__ emb,
                        float* __restrict__ h, float* __restrict__ res){
  int idx = blockIdx.x * 256 + threadIdx.x;
  int t = idx >> 10, d = idx & 1023;
  h[idx] = emb[(size_t)ids[t] * D_ + d];
  res[idx] = 0.f;
}

__global__ void k_zero_i32(int* __restrict__ p, int n){
  int i = blockIdx.x * 64 + threadIdx.x;
  if (i < n) p[i] = 0;
}

// ---------------- fused: res += h; out = rms(res) * w ----------------
__global__ __launch_bounds__(256)
void k_fused_rms(float* __restrict__ res, const float* __restrict__ h,
                 const float* __restrict__ w, float* __restrict__ out){
  int t = blockIdx.x, tid = threadIdx.x;
  float* rr = res + (size_t)t * D_;
  const float* hr = h + (size_t)t * D_;
  float ss = 0.f;
  float vloc[4];
  #pragma unroll
  for (int u = 0; u < 4; u++){
    int d = tid + u * 256;
    float v = rr[d] + hr[d];
    vloc[u] = v;
    ss += v * v;
  }
  #pragma unroll
  for (int o = 32; o; o >>= 1) ss += __shfl_xor(ss, o);
  __shared__ float red[4];
  if ((tid & 63) == 0) red[tid >> 6] = ss;
  __syncthreads();
  float r = rsqrtf((red[0] + red[1] + red[2] + red[3]) * (1.f / D_) + 1e-6f);
  float* orow = out + (size_t)t * D_;
  #pragma unroll
  for (int u = 0; u < 4; u++){
    int d = tid + u * 256;
    rr[d] = vloc[u];
    orow[d] = vloc[u] * r * w[d];
  }
}

// ---------------- per-head RMSNorm + RoPE (in place) ----------------
__global__ __launch_bounds__(64)
void k_qknorm_rope(float* __restrict__ buf, const float* __restrict__ nw,
                   const int* __restrict__ pos, int nheads){
  int row = blockIdx.x;
  int t = row / nheads;
  int lane = threadIdx.x;
  int base = row * DH_ + lane;
  float x = buf[base];
  float ss = x * x;
  #pragma unroll
  for (int o = 32; o; o >>= 1) ss += __shfl_xor(ss, o);
  float r = rsqrtf(ss * (1.f / DH_) + 1e-6f);
  float xn = x * r * nw[lane];
  int j = lane & 31;
  float inv = powf(1.0e6f, -(float)j * (1.f / 32.f));
  float ang = (float)pos[t] * inv;
  float s, c;
  sincosf(ang, &s, &c);
  float p = __shfl_xor(xn, 32);
  float rot = (lane < 32) ? -p : p;
  buf[base] = xn * c + rot * s;
}

// ---------------- MFMA flash attention: one block per (head, 64-query tile) ----
// Split-bf16 (hi+lo, 3-MFMA) everywhere: QK^T = QhKh+QhKl+QlKh, PV = PhVh+PhVl+PlVh.
// Fragment layout mirrors the verified GEMM core below:
//   A-frag: lane holds A[row=l16][k=lq*8+32s]   (Q from regs, P from LDS [r][c])
//   B-frag: lane holds B[k=lq*8+32s][col=l16]   (K stored [c][d], V stored transposed [d][c])
//   D-tile: row = lq*4+i, col = l16.
// Each of the 4 waves owns 16 q-rows (w*16..w*16+15); P is wave-private in LDS.
__global__ __launch_bounds__(256)
void k_fattn(const float* __restrict__ q, const float* __restrict__ k,
             const float* __restrict__ v, float* __restrict__ out){
  const int h = blockIdx.x, qt = blockIdx.y;
  const int kvh = h >> 2;
  const int tid = threadIdx.x;
  const int w = tid >> 6, lane = tid & 63, l16 = lane & 15, lq = lane >> 4;

  __shared__ __align__(16) short Kh[64][72], Kl[64][72];
  __shared__ __align__(16) short Vth[64][72], Vtl[64][72];
  __shared__ __align__(16) short Ph[64][72], Pl[64][72];

  // ---- Q fragments, kept in registers for the whole block ----
  short8 qh[2], ql[2];
  {
    const float* qp = q + ((size_t)(qt * 64 + w * 16 + l16) * H_ + h) * DH_;
    #pragma unroll
    for (int s = 0; s < 2; s++){
      float a8[8];
      *(float4*)&a8[0] = *(const float4*)(qp + lq * 8 + 32 * s);
      *(float4*)&a8[4] = *(const float4*)(qp + lq * 8 + 32 * s + 4);
      split8(a8, qh[s], ql[s]);
    }
  }

  float m_i[4], l_i[4];
  f32x4 acc[4];
  #pragma unroll
  for (int i = 0; i < 4; i++){ m_i[i] = -1e30f; l_i[i] = 0.f; acc[i] = (f32x4){0.f,0.f,0.f,0.f}; }

  // staging roles
  const int kc = tid >> 2, kd = (tid & 3) * 16;       // K: row c, 16-wide d segment
  const int vc0 = (tid & 15) * 4, vd0 = (tid >> 4) * 4; // V: 4x4 sub-tile (reg transpose)
  float kr[16], vr[16];

  // prefetch kt=0
  {
    const float* kp = k + ((size_t)(0 + kc) * KV_ + kvh) * DH_ + kd;
    #pragma unroll
    for (int u = 0; u < 16; u += 4) *(float4*)&kr[u] = *(const float4*)(kp + u);
    #pragma unroll
    for (int cc = 0; cc < 4; cc++){
      const float* vp = v + ((size_t)(0 + vc0 + cc) * KV_ + kvh) * DH_ + vd0;
      *(float4*)&vr[cc * 4] = *(const float4*)vp;
    }
  }

  for (int kt = 0; kt <= qt; kt++){
    __syncthreads();            // prior iteration's LDS reads complete
    // ---- stage K (bf16 hi/lo, [c][d]) and V (transposed, [d][c]) ----
    {
      short8 h8, l8;
      split8(&kr[0], h8, l8);
      *(short8*)&Kh[kc][kd] = h8;     *(short8*)&Kl[kc][kd] = l8;
      split8(&kr[8], h8, l8);
      *(short8*)&Kh[kc][kd + 8] = h8; *(short8*)&Kl[kc][kd + 8] = l8;
      #pragma unroll
      for (int dd = 0; dd < 4; dd++){
        short4v hv, lv;
        #pragma unroll
        for (int cc = 0; cc < 4; cc++){
          float f = vr[cc * 4 + dd];
          short hb = f2bf(f);
          hv[cc] = hb;
          lv[cc] = f2bf(f - bf2f(hb));
        }
        *(short4v*)&Vth[vd0 + dd][vc0] = hv;
        *(short4v*)&Vtl[vd0 + dd][vc0] = lv;
      }
    }
    __syncthreads();
    // prefetch next tile (latency hidden under compute)
    if (kt < qt){
      const float* kp = k + ((size_t)((kt + 1) * 64 + kc) * KV_ + kvh) * DH_ + kd;
      #pragma unroll
      for (int u = 0; u < 16; u += 4) *(float4*)&kr[u] = *(const float4*)(kp + u);
      #pragma unroll
      for (int cc = 0; cc < 4; cc++){
        const float* vp = v + ((size_t)((kt + 1) * 64 + vc0 + cc) * KV_ + kvh) * DH_ + vd0;
        *(float4*)&vr[cc * 4] = *(const float4*)vp;
      }
    }

    // ---- S = Q K^T (split-bf16, 3 MFMA per tile per k-step) ----
    f32x4 sa[4];
    #pragma unroll
    for (int ct = 0; ct < 4; ct++) sa[ct] = (f32x4){0.f,0.f,0.f,0.f};
    #pragma unroll
    for (int s = 0; s < 2; s++){
      #pragma unroll
      for (int ct = 0; ct < 4; ct++){
        short8 kh8 = *(const short8*)&Kh[ct * 16 + l16][lq * 8 + 32 * s];
        short8 kl8 = *(const short8*)&Kl[ct * 16 + l16][lq * 8 + 32 * s];
        sa[ct] = __builtin_amdgcn_mfma_f32_16x16x32_bf16(qh[s], kh8, sa[ct], 0, 0, 0);
        sa[ct] = __builtin_amdgcn_mfma_f32_16x16x32_bf16(qh[s], kl8, sa[ct], 0, 0, 0);
        sa[ct] = __builtin_amdgcn_mfma_f32_16x16x32_bf16(ql[s], kh8, sa[ct], 0, 0, 0);
      }
    }

    // ---- scale + causal mask ----
    const bool diag = (kt == qt);
    #pragma unroll
    for (int ct = 0; ct < 4; ct++)
      #pragma unroll
      for (int i = 0; i < 4; i++){
        float sv = sa[ct][i] * 0.125f;
        if (diag && (ct * 16 + l16 > w * 16 + lq * 4 + i)) sv = -1e30f;
        sa[ct][i] = sv;
      }

    // ---- online softmax (rows live in 16-lane groups) ----
    #pragma unroll
    for (int i = 0; i < 4; i++){
      float mx = fmaxf(fmaxf(sa[0][i], sa[1][i]), fmaxf(sa[2][i], sa[3][i]));
      #pragma unroll
      for (int o = 8; o; o >>= 1) mx = fmaxf(mx, __shfl_xor(mx, o));
      float mn = fmaxf(m_i[i], mx);
      float al = __expf(m_i[i] - mn);
      float ls = 0.f;
      #pragma unroll
      for (int ct = 0; ct < 4; ct++){
        float pv = __expf(sa[ct][i] - mn);
        sa[ct][i] = pv;
        ls += pv;
      }
      #pragma unroll
      for (int o = 8; o; o >>= 1) ls += __shfl_xor(ls, o);
      l_i[i] = l_i[i] * al + ls;
      m_i[i] = mn;
      #pragma unroll
      for (int dt = 0; dt < 4; dt++) acc[dt][i] *= al;
    }

    // ---- P -> LDS as bf16 hi/lo (wave-private rows) ----
    {
      int pr = w * 16 + lq * 4;
      #pragma unroll
      for (int i = 0; i < 4; i++)
        #pragma unroll
        for (int ct = 0; ct < 4; ct++){
          float pv = sa[ct][i];
          short hb = f2bf(pv);
          Ph[pr + i][ct * 16 + l16] = hb;
          Pl[pr + i][ct * 16 + l16] = f2bf(pv - bf2f(hb));
        }
    }
    __syncthreads();   // order P writes vs frag reads (also covers V staging)

    // ---- O += P V (split-bf16) ----
    #pragma unroll
    for (int s = 0; s < 2; s++){
      short8 pah = *(const short8*)&Ph[w * 16 + l16][lq * 8 + 32 * s];
      short8 pal = *(const short8*)&Pl[w * 16 + l16][lq * 8 + 32 * s];
      #pragma unroll
      for (int dt = 0; dt < 4; dt++){
        short8 vh8 = *(const short8*)&Vth[dt * 16 + l16][lq * 8 + 32 * s];
        short8 vl8 = *(const short8*)&Vtl[dt * 16 + l16][lq * 8 + 32 * s];
        acc[dt] = __builtin_amdgcn_mfma_f32_16x16x32_bf16(pah, vh8, acc[dt], 0, 0, 0);
        acc[dt] = __builtin_amdgcn_mfma_f32_16x16x32_bf16(pah, vl8, acc[dt], 0, 0, 0);
        acc[dt] = __builtin_amdgcn_mfma_f32_16x16x32_bf16(pal, vh8, acc[dt], 0, 0, 0);
      }
    }
  }

  // ---- epilogue ----
  int orow = qt * 64 + w * 16 + lq * 4;
  #pragma unroll
  for (int i = 0; i < 4; i++){
    float inv = 1.f / l_i[i];
    #pragma unroll
    for (int dt = 0; dt < 4; dt++)
      out[(size_t)(orow + i) * (H_ * DH_) + h * DH_ + dt * 16 + l16] = acc[dt][i] * inv;
  }
}

// ======= split-bf16 MFMA GEMM core (vectored LDS staging + reg prefetch) =======
// LDS: [64][40] shorts, pitch 80 B (16B-aligned rows, <=2-way conflicts).
// Staging: thread owns row/col sm=tid&63, k-octet sk=(tid>>6)*8.
//   A: 2x float4 (contiguous k).  B: 8 k-strided dwords (256B coalesced/instr).
//   Writes: one ds_write_b128 hi + one lo each for A and B.

#define GEMM_LDS  __shared__ __align__(16) short Ah[64][40], Al[64][40], Bh[64][40], Bl[64][40]

// ---------------- generic: C[M,N] = A[M,K] @ B[K,N] ----------------
__global__ __launch_bounds__(256)
void k_mgemm(const float* __restrict__ A, const float* __restrict__ B,
             float* __restrict__ C, int M, int N, int K){
  GEMM_LDS;
  int tid = threadIdx.x;
  int row0 = blockIdx.y * 64, col0 = blockIdx.x * 64;
  int w = tid >> 6, lane = tid & 63, l16 = lane & 15, lq = lane >> 4;
  int sm = tid & 63, sk = (tid >> 6) * 8;
  bool aok = (row0 + sm) < M;
  const float* Arow = A + (size_t)(row0 + sm) * K + sk;
  const float* Bcol = B + (size_t)sk * N + col0 + sm;
  f32x4 acc[4] = {};
  float a_reg[8], b_reg[8];
  if (aok){
    *(float4*)&a_reg[0] = *(const float4*)(Arow);
    *(float4*)&a_reg[4] = *(const float4*)(Arow + 4);
  } else {
    #pragma unroll
    for (int j = 0; j < 8; j++) a_reg[j] = 0.f;
  }
  #pragma unroll
  for (int j = 0; j < 8; j++) b_reg[j] = Bcol[(size_t)j * N];
  int nc = K >> 5;
  for (int c = 0; c < nc; c++){
    short8 h8, l8;
    split8(a_reg, h8, l8);
    *(short8*)&Ah[sm][sk] = h8;
    *(short8*)&Al[sm][sk] = l8;
    split8(b_reg, h8, l8);
    *(short8*)&Bh[sm][sk] = h8;
    *(short8*)&Bl[sm][sk] = l8;
    __syncthreads();
    if (c + 1 < nc){
      const float* An = Arow + (c + 1) * 32;
      if (aok){
        *(float4*)&a_reg[0] = *(const float4*)(An);
        *(float4*)&a_reg[4] = *(const float4*)(An + 4);
      }
      const float* Bn = Bcol + (size_t)(c + 1) * 32 * N;
      #pragma unroll
      for (int j = 0; j < 8; j++) b_reg[j] = Bn[(size_t)j * N];
    }
    short8 ah = *(const short8*)&Ah[w * 16 + l16][lq * 8];
    short8 al = *(const short8*)&Al[w * 16 + l16][lq * 8];
    #pragma unroll
    for (int nt = 0; nt < 4; nt++){
      short8 bh = *(const short8*)&Bh[nt * 16 + l16][lq * 8];
      short8 bl = *(const short8*)&Bl[nt * 16 + l16][lq * 8];
      acc[nt] = __builtin_amdgcn_mfma_f32_16x16x32_bf16(ah, bh, acc[nt], 0, 0, 0);
      acc[nt] = __builtin_amdgcn_mfma_f32_16x16x32_bf16(ah, bl, acc[nt], 0, 0, 0);
      acc[nt] = __builtin_amdgcn_mfma_f32_16x16x32_bf16(al, bh, acc[nt], 0, 0, 0);
    }
    __syncthreads();
  }
  #pragma unroll
  for (int nt = 0; nt < 4; nt++)
    #pragma unroll
    for (int i = 0; i < 4; i++){
      int r = row0 + w * 16 + lq * 4 + i;
      if (r < M) C[(size_t)r * N + col0 + nt * 16 + l16] = acc[nt][i];
    }
}

// ---------------- expert up: gathered A rows ----------------
__global__ __launch_bounds__(256)
void k_mgemm_up(const float* __restrict__ hn, const float* __restrict__ egu_l,
                float* __restrict__ G, const int* __restrict__ counts,
                const int* __restrict__ offsets, const int* __restrict__ rowtok){
  const int e = blockIdx.z;
  const int me = counts[e];
  const int row0 = blockIdx.y * 64;
  if (row0 >= me) return;
  const int off = offsets[e];
  const float* B = egu_l + (size_t)e * D_ * (2 * F_);
  const int N = 2 * F_, K = D_;
  GEMM_LDS;
  int tid = threadIdx.x;
  int col0 = blockIdx.x * 64;
  int w = tid >> 6, lane = tid & 63, l16 = lane & 15, lq = lane >> 4;
  int sm = tid & 63, sk = (tid >> 6) * 8;
  bool aok = (row0 + sm) < me;
  int tok = aok ? rowtok[off + row0 + sm] : 0;
  const float* Arow = hn + (size_t)tok * K + sk;
  const float* Bcol = B + (size_t)sk * N + col0 + sm;
  f32x4 acc[4] = {};
  float a_reg[8], b_reg[8];
  if (aok){
    *(float4*)&a_reg[0] = *(const float4*)(Arow);
    *(float4*)&a_reg[4] = *(const float4*)(Arow + 4);
  } else {
    #pragma unroll
    for (int j = 0; j < 8; j++) a_reg[j] = 0.f;
  }
  #pragma unroll
  for (int j = 0; j < 8; j++) b_reg[j] = Bcol[(size_t)j * N];
  int nc = K >> 5;
  for (int c = 0; c < nc; c++){
    short8 h8, l8;
    split8(a_reg, h8, l8);
    *(short8*)&Ah[sm][sk] = h8;
    *(short8*)&Al[sm][sk] = l8;
    split8(b_reg, h8, l8);
    *(short8*)&Bh[sm][sk] = h8;
    *(short8*)&Bl[sm][sk] = l8;
    __syncthreads();
    if (c + 1 < nc){
      const float* An = Arow + (c + 1) * 32;
      if (aok){
        *(float4*)&a_reg[0] = *(const float4*)(An);
        *(float4*)&a_reg[4] = *(const float4*)(An + 4);
      }
      const float* Bn = Bcol + (size_t)(c + 1) * 32 * N;
      #pragma unroll
      for (int j = 0; j < 8; j++) b_reg[j] = Bn[(size_t)j * N];
    }
    short8 ah = *(const short8*)&Ah[w * 16 + l16][lq * 8];
    short8 al = *(const short8*)&Al[w * 16 + l16][lq * 8];
    #pragma unroll
    for (int nt = 0; nt < 4; nt++){
      short8 bh = *(const short8*)&Bh[nt * 16 + l16][lq * 8];
      short8 bl = *(const short8*)&Bl[nt * 16 + l16][lq * 8];
      acc[nt] = __builtin_amdgcn_mfma_f32_16x16x32_bf16(ah, bh, acc[nt], 0, 0, 0);
      acc[nt] = __builtin_amdgcn_mfma_f32_16x16x32_bf16(ah, bl, acc[nt], 0, 0, 0);
      acc[nt] = __builtin_amdgcn_mfma_f32_16x16x32_bf16(al, bh, acc[nt], 0, 0, 0);
    }
    __syncthreads();
  }
  #pragma unroll
  for (int nt = 0; nt < 4; nt++)
    #pragma unroll
    for (int i = 0; i < 4; i++){
      int r = row0 + w * 16 + lq * 4 + i;
      if (r < me) G[(size_t)(off + r) * N + col0 + nt * 16 + l16] = acc[nt][i];
    }
}

// ---------------- expert down: + weighted scatter-add ----------------
__global__ __launch_bounds__(256)
void k_mgemm_dn(const float* __restrict__ he, const float* __restrict__ edn_l,
                float* __restrict__ routed, const int* __restrict__ counts,
                const int* __restrict__ offsets, const int* __restrict__ rowtok,
                const float* __restrict__ roww){
  const int e = blockIdx.z;
  const int me = counts[e];
  const int row0 = blockIdx.y * 64;
  if (row0 >= me) return;
  const int off = offsets[e];
  const float* B = edn_l + (size_t)e * F_ * D_;
  const int N = D_, K = F_;
  GEMM_LDS;
  int tid = threadIdx.x;
  int col0 = blockIdx.x * 64;
  int w = tid >> 6, lane = tid & 63, l16 = lane & 15, lq = lane >> 4;
  int sm = tid & 63, sk = (tid >> 6) * 8;
  bool aok = (row0 + sm) < me;
  const float* Arow = he + (size_t)(off + row0 + (aok ? sm : 0)) * K + sk;
  const float* Bcol = B + (size_t)sk * N + col0 + sm;
  f32x4 acc[4] = {};
  float a_reg[8], b_reg[8];
  if (aok){
    *(float4*)&a_reg[0] = *(const float4*)(Arow);
    *(float4*)&a_reg[4] = *(const float4*)(Arow + 4);
  } else {
    #pragma unroll
    for (int j = 0; j < 8; j++) a_reg[j] = 0.f;
  }
  #pragma unroll
  for (int j = 0; j < 8; j++) b_reg[j] = Bcol[(size_t)j * N];
  int nc = K >> 5;
  for (int c = 0; c < nc; c++){
    short8 h8, l8;
    split8(a_reg, h8, l8);
    *(short8*)&Ah[sm][sk] = h8;
    *(short8*)&Al[sm][sk] = l8;
    split8(b_reg, h8, l8);
    *(short8*)&Bh[sm][sk] = h8;
    *(short8*)&Bl[sm][sk] = l8;
    __syncthreads();
    if (c + 1 < nc){
      const float* An = Arow + (c + 1) * 32;
      if (aok){
        *(float4*)&a_reg[0] = *(const float4*)(An);
        *(float4*)&a_reg[4] = *(const float4*)(An + 4);
      }
      const float* Bn = Bcol + (size_t)(c + 1) * 32 * N;
      #pragma unroll
      for (int j = 0; j < 8; j++) b_reg[j] = Bn[(size_t)j * N];
    }
    short8 ah = *(const short8*)&Ah[w * 16 + l16][lq * 8];
    short8 al = *(const short8*)&Al[w * 16 + l16][lq * 8];
    #pragma unroll
    for (int nt = 0; nt < 4; nt++){
      short8 bh = *(const short8*)&Bh[nt * 16 + l16][lq * 8];
      short8 bl = *(const short8*)&Bl[nt * 16 + l16][lq * 8];
      acc[nt] = __builtin_amdgcn_mfma_f32_16x16x32_bf16(ah, bh, acc[nt], 0, 0, 0);
      acc[nt] = __builtin_amdgcn_mfma_f32_16x16x32_bf16(ah, bl, acc[nt], 0, 0, 0);
      acc[nt] = __builtin_amdgcn_mfma_f32_16x16x32_bf16(al, bh, acc[nt], 0, 0, 0);
    }
    __syncthreads();
  }
  #pragma unroll
  for (int i = 0; i < 4; i++){
    int r = row0 + w * 16 + lq * 4 + i;
    if (r < me){
      int tok = rowtok[off + r];
      float wgt = roww[off + r];
      float* cp = routed + (size_t)tok * D_ + col0;
      #pragma unroll
      for (int nt = 0; nt < 4; nt++)
        atomicAdd(&cp[nt * 16 + l16], wgt * acc[nt][i]);
    }
  }
}

// ---------------- SiLU(gate)*up ----------------
__global__ void k_silumul(const float* __restrict__ g, float* __restrict__ out,
                          int width, int half){
  int idx = blockIdx.x * 256 + threadIdx.x;
  int r = idx / half, f = idx - r * half;
  float a = g[(size_t)r * width + f];
  float b = g[(size_t)r * width + half + f];
  out[idx] = a * b / (1.f + __expf(-a));
}

// ---------------- shared-expert sigmoid gate ----------------
__global__ __launch_bounds__(256)
void k_gate(const float* __restrict__ hn, const float* __restrict__ sg,
            float* __restrict__ gate){
  int t = blockIdx.x, tid = threadIdx.x;
  const float* xr = hn + (size_t)t * D_;
  float s = 0.f;
  for (int d = tid; d < D_; d += 256) s += xr[d] * sg[d];
  #pragma unroll
  for (int o = 32; o; o >>= 1) s += __shfl_xor(s, o);
  __shared__ float red[4];
  if ((tid & 63) == 0) red[tid >> 6] = s;
  __syncthreads();
  if (tid == 0){
    float tot = red[0] + red[1] + red[2] + red[3];
    gate[t] = 1.f / (1.f + __expf(-tot));
  }
}

// ---------------- router: softmax + top-2 + renorm ----------------
__global__ __launch_bounds__(64)
void k_router(const float* __restrict__ hn, const float* __restrict__ rw,
              int* __restrict__ counts, int* __restrict__ top_e,
              float* __restrict__ top_w){
  int t = blockIdx.x;
  int lane = threadIdx.x;
  int e = lane & 7, c = lane >> 3;
  const float* xr = hn + (size_t)t * D_;
  float s = 0.f;
  for (int d = c * 128; d < c * 128 + 128; d++) s += xr[d] * rw[d * E_ + e];
  s += __shfl_down(s, 32);
  s += __shfl_down(s, 16);
  s += __shfl_down(s, 8);
  float v[8];
  #pragma unroll
  for (int qq = 0; qq < 8; qq++) v[qq] = __shfl(s, qq);
  if (lane == 0){
    float mx = v[0];
    #pragma unroll
    for (int qq = 1; qq < 8; qq++) mx = fmaxf(mx, v[qq]);
    float p[8];
    #pragma unroll
    for (int qq = 0; qq < 8; qq++) p[qq] = __expf(v[qq] - mx);
    int i0 = 0;
    #pragma unroll
    for (int qq = 1; qq < 8; qq++) if (p[qq] > p[i0]) i0 = qq;
    int i1 = (i0 == 0) ? 1 : 0;
    #pragma unroll
    for (int qq = 0; qq < 8; qq++) if (qq != i0 && p[qq] > p[i1]) i1 = qq;
    float w0 = p[i0], w1 = p[i1];
    float inv = 1.f / (w0 + w1);
    top_e[t * 2 + 0] = i0; top_w[t * 2 + 0] = w0 * inv;
    top_e[t * 2 + 1] = i1; top_w[t * 2 + 1] = w1 * inv;
    atomicAdd(&counts[i0], 1);
    atomicAdd(&counts[i1], 1);
  }
}

__global__ void k_prefix(const int* __restrict__ counts, int* __restrict__ offsets,
                         int* __restrict__ cursor){
  if (threadIdx.x == 0 && blockIdx.x == 0){
    int acc = 0;
    for (int e = 0; e < E_; e++){ offsets[e] = acc; cursor[e] = acc; acc += counts[e]; }
  }
}

__global__ void k_assign(const int* __restrict__ top_e, const float* __restrict__ top_w,
                         int* __restrict__ cursor, int* __restrict__ rowtok,
                         float* __restrict__ roww){
  int i = blockIdx.x * 256 + threadIdx.x;
  if (i >= T_ * TOPK_) return;
  int e = top_e[i];
  int slot = atomicAdd(&cursor[e], 1);
  rowtok[slot] = i >> 1;
  roww[slot] = top_w[i];
}

// ---------------- h = shared * gate[t]  (experts scatter-add on top) ----------------
__global__ void k_prefill(float* __restrict__ h, const float* __restrict__ shexp,
                          const float* __restrict__ gate){
  int idx = blockIdx.x * 256 + threadIdx.x;
  h[idx] = shexp[idx] * gate[idx >> 10];
}

// ---------------- final: out = rms(res + h, final_ln), fp32 out ----------------
__global__ __launch_bounds__(256)
void k_final_rms(const float* __restrict__ resv, const float* __restrict__ hv,
                 const float* __restrict__ w, float* __restrict__ out){
  int t = blockIdx.x, tid = threadIdx.x;
  const float* xr = resv + (size_t)t * D_;
  const float* hr = hv + (size_t)t * D_;
  float ss = 0.f;
  for (int d = tid; d < D_; d += 256){ float v = xr[d] + hr[d]; ss += v * v; }
  #pragma unroll
  for (int o = 32; o; o >>= 1) ss += __shfl_xor(ss, o);
  __shared__ float red[4];
  if ((tid & 63) == 0) red[tid >> 6] = ss;
  __syncthreads();
  float r = rsqrtf((red[0] + red[1] + red[2] + red[3]) * (1.f / D_) + 1e-6f);
  float* orow = out + (size_t)t * D_;
  for (int d = tid; d < D_; d += 256) orow[d] = (xr[d] + hr[d]) * r * w[d];
}

extern "C" void kernel_launch(void* const* d_in, const int* in_sizes, int n_in,
                              void* d_out, int out_size, void* d_ws, size_t ws_size,
                              hipStream_t stream){
  (void)in_sizes; (void)n_in; (void)out_size; (void)ws_size;
  const int* ids = (const int*)d_in[0];
  const int* pos = (const int*)d_in[1];
  const float* emb = (const float*)d_in[2];
  const float* ln1 = (const float*)d_in[3];
  const float* wq  = (const float*)d_in[4];
  const float* wk  = (const float*)d_in[5];
  const float* wv  = (const float*)d_in[6];
  const float* wo  = (const float*)d_in[7];
  const float* qn  = (const float*)d_in[8];
  const float* kn  = (const float*)d_in[9];
  const float* ln2 = (const float*)d_in[10];
  const float* rw  = (const float*)d_in[11];
  const float* egu = (const float*)d_in[12];
  const float* edn = (const float*)d_in[13];
  const float* sgu = (const float*)d_in[14];
  const float* sdn = (const float*)d_in[15];
  const float* sg  = (const float*)d_in[16];
  const float* fln = (const float*)d_in[17];

  float* ws = (float*)d_ws;
  const size_t MB = (size_t)1 << 20;
  float* res    = ws;
  float* h      = ws + 1 * MB;
  float* hn     = ws + 2 * MB;
  float* qlin   = ws + 3 * MB;
  float* kbuf   = ws + 4 * MB;
  float* vbuf   = kbuf + T_ * KV_ * DH_;
  float* attnb  = ws + 5 * MB;
  float* gu     = ws + 6 * MB;
  float* sact   = ws + 10 * MB;
  float* shexp  = ws + 12 * MB;
  float* G      = ws + 13 * MB;
  float* he     = ws + 15 * MB;
  float* gate   = ws + 17 * MB;
  float* roww   = gate + 4096;
  float* top_w  = roww + 4096;
  int* counts   = (int*)(top_w + 4096);
  int* offsets  = counts + 8;
  int* cursor   = offsets + 8;
  int* top_e    = cursor + 8;
  int* rowtok   = top_e + 2048;

  const int NTD = T_ * D_ / 256;

  k_embed<<<NTD, 256, 0, stream>>>(ids, emb, h, res);

  for (int i = 0; i < L_; i++){
    // ---- attention ----
    k_fused_rms<<<T_, 256, 0, stream>>>(res, h, ln1 + (size_t)i * D_, hn);
    k_mgemm<<<dim3(16, 16), 256, 0, stream>>>(hn, wq + (size_t)i * D_ * (H_ * DH_), qlin, T_, H_ * DH_, D_);
    k_mgemm<<<dim3(4, 16), 256, 0, stream>>>(hn, wk + (size_t)i * D_ * (KV_ * DH_), kbuf, T_, KV_ * DH_, D_);
    k_mgemm<<<dim3(4, 16), 256, 0, stream>>>(hn, wv + (size_t)i * D_ * (KV_ * DH_), vbuf, T_, KV_ * DH_, D_);
    k_qknorm_rope<<<T_ * H_, 64, 0, stream>>>(qlin, qn + (size_t)i * DH_, pos, H_);
    k_qknorm_rope<<<T_ * KV_, 64, 0, stream>>>(kbuf, kn + (size_t)i * DH_, pos, KV_);
    k_fattn<<<dim3(H_, T_ / 64), 256, 0, stream>>>(qlin, kbuf, vbuf, attnb);
    k_mgemm<<<dim3(16, 16), 256, 0, stream>>>(attnb, wo + (size_t)i * (H_ * DH_) * D_, h, T_, D_, H_ * DH_);
    // ---- MoE MLP ----
    k_fused_rms<<<T_, 256, 0, stream>>>(res, h, ln2 + (size_t)i * D_, hn);
    k_mgemm<<<dim3(64, 16), 256, 0, stream>>>(hn, sgu + (size_t)i * D_ * (2 * FS_), gu, T_, 2 * FS_, D_);
    k_silumul<<<T_ * FS_ / 256, 256, 0, stream>>>(gu, sact, 2 * FS_, FS_);
    k_mgemm<<<dim3(16, 16), 256, 0, stream>>>(sact, sdn + (size_t)i * FS_ * D_, shexp, T_, D_, FS_);
    k_gate<<<T_, 256, 0, stream>>>(hn, sg + (size_t)i * D_, gate);
    k_zero_i32<<<1, 64, 0, stream>>>(counts, 8);
    k_router<<<T_, 64, 0, stream>>>(hn, rw + (size_t)i * D_ * E_, counts, top_e, top_w);
    k_prefix<<<1, 1, 0, stream>>>(counts, offsets, cursor);
    k_assign<<<8, 256, 0, stream>>>(top_e, top_w, cursor, rowtok, roww);
    k_mgemm_up<<<dim3(16, 32, 8), 256, 0, stream>>>(hn, egu + (size_t)i * E_ * D_ * (2 * F_), G, counts, offsets, rowtok);
    k_silumul<<<T_ * TOPK_ * F_ / 256, 256, 0, stream>>>(G, he, 2 * F_, F_);
    k_prefill<<<NTD, 256, 0, stream>>>(h, shexp, gate);
    k_mgemm_dn<<<dim3(16, 32, 8), 256, 0, stream>>>(he, edn + (size_t)i * E_ * F_ * D_, h, counts, offsets, rowtok, roww);
  }

  k_final_rms<<<T_, 256, 0, stream>>>(res, h, fln, (float*)d_out);
}

// Round 4
// 907.354 us; speedup vs baseline: 1.3955x; 1.2477x over previous
//
#include <hip/hip_runtime.h>
#include <hip/hip_bf16.h>

#define T_ 1024
#define D_ 1024
#define H_ 16
#define KV_ 4
#define DH_ 64
#define E_ 8
#define TOPK_ 2
#define F_ 512
#define FS_ 2048
#define L_ 2

typedef unsigned int uint32;
typedef __attribute__((ext_vector_type(8))) short short8;
typedef __attribute__((ext_vector_type(4))) short short4v;
typedef __attribute__((ext_vector_type(4))) float f32x4;

__device__ __forceinline__ short f2bf(float f){   // RNE fp32 -> bf16 bits
  uint32 u = __float_as_uint(f);
  return (short)((u + 0x7fffu + ((u >> 16) & 1u)) >> 16);
}
__device__ __forceinline__ float bf2f(short s){
  return __uint_as_float(((uint32)(unsigned short)s) << 16);
}

__device__ __forceinline__ void split8(const float* src, short8& h8, short8& l8){
  #pragma unroll
  for (int j = 0; j < 8; j++){
    short hi = f2bf(src[j]);
    h8[j] = hi;
    l8[j] = f2bf(src[j] - bf2f(hi));
  }
}

// ---------------- embedding gather + zero residual ----------------
__global__ void k_embed(const int* __restrict__ ids, const float* __restrict__ emb,
                        float* __restrict__ h, float* __restrict__ res){
  int idx = blockIdx.x * 256 + threadIdx.x;
  int t = idx >> 10, d = idx & 1023;
  h[idx] = emb[(size_t)ids[t] * D_ + d];
  res[idx] = 0.f;
}

__global__ void k_zero_i32(int* __restrict__ p, int n){
  int i = blockIdx.x * 64 + threadIdx.x;
  if (i < n) p[i] = 0;
}

// ---------------- fused: res += h; out = rms(res) * w ----------------
__global__ __launch_bounds__(256)
void k_fused_rms(float* __restrict__ res, const float* __restrict__ h,
                 const float* __restrict__ w, float* __restrict__ out){
  int t = blockIdx.x, tid = threadIdx.x;
  float* rr = res + (size_t)t * D_;
  const float* hr = h + (size_t)t * D_;
  float ss = 0.f;
  float vloc[4];
  #pragma unroll
  for (int u = 0; u < 4; u++){
    int d = tid + u * 256;
    float v = rr[d] + hr[d];
    vloc[u] = v;
    ss += v * v;
  }
  #pragma unroll
  for (int o = 32; o; o >>= 1) ss += __shfl_xor(ss, o);
  __shared__ float red[4];
  if ((tid & 63) == 0) red[tid >> 6] = ss;
  __syncthreads();
  float r = rsqrtf((red[0] + red[1] + red[2] + red[3]) * (1.f / D_) + 1e-6f);
  float* orow = out + (size_t)t * D_;
  #pragma unroll
  for (int u = 0; u < 4; u++){
    int d = tid + u * 256;
    rr[d] = vloc[u];
    orow[d] = vloc[u] * r * w[d];
  }
}

// ---- variant: h = h0 + h1 (K-split partials), res += h; out = rms(res)*w ----
__global__ __launch_bounds__(256)
void k_fused_rms2(float* __restrict__ res, const float* __restrict__ h0,
                  const float* __restrict__ h1,
                  const float* __restrict__ w, float* __restrict__ out){
  int t = blockIdx.x, tid = threadIdx.x;
  float* rr = res + (size_t)t * D_;
  const float* h0r = h0 + (size_t)t * D_;
  const float* h1r = h1 + (size_t)t * D_;
  float ss = 0.f;
  float vloc[4];
  #pragma unroll
  for (int u = 0; u < 4; u++){
    int d = tid + u * 256;
    float v = rr[d] + h0r[d] + h1r[d];
    vloc[u] = v;
    ss += v * v;
  }
  #pragma unroll
  for (int o = 32; o; o >>= 1) ss += __shfl_xor(ss, o);
  __shared__ float red[4];
  if ((tid & 63) == 0) red[tid >> 6] = ss;
  __syncthreads();
  float r = rsqrtf((red[0] + red[1] + red[2] + red[3]) * (1.f / D_) + 1e-6f);
  float* orow = out + (size_t)t * D_;
  #pragma unroll
  for (int u = 0; u < 4; u++){
    int d = tid + u * 256;
    rr[d] = vloc[u];
    orow[d] = vloc[u] * r * w[d];
  }
}

// ---------------- per-head RMSNorm + RoPE (in place) ----------------
__global__ __launch_bounds__(64)
void k_qknorm_rope(float* __restrict__ buf, const float* __restrict__ nw,
                   const int* __restrict__ pos, int nheads){
  int row = blockIdx.x;
  int t = row / nheads;
  int lane = threadIdx.x;
  int base = row * DH_ + lane;
  float x = buf[base];
  float ss = x * x;
  #pragma unroll
  for (int o = 32; o; o >>= 1) ss += __shfl_xor(ss, o);
  float r = rsqrtf(ss * (1.f / DH_) + 1e-6f);
  float xn = x * r * nw[lane];
  int j = lane & 31;
  float inv = powf(1.0e6f, -(float)j * (1.f / 32.f));
  float ang = (float)pos[t] * inv;
  float s, c;
  sincosf(ang, &s, &c);
  float p = __shfl_xor(xn, 32);
  float rot = (lane < 32) ? -p : p;
  buf[base] = xn * c + rot * s;
}

// ---------------- MFMA flash attention: one block per (head, 64-query tile) ----
__global__ __launch_bounds__(256)
void k_fattn(const float* __restrict__ q, const float* __restrict__ k,
             const float* __restrict__ v, float* __restrict__ out){
  const int h = blockIdx.x, qt = blockIdx.y;
  const int kvh = h >> 2;
  const int tid = threadIdx.x;
  const int w = tid >> 6, lane = tid & 63, l16 = lane & 15, lq = lane >> 4;

  __shared__ __align__(16) short Kh[64][72], Kl[64][72];
  __shared__ __align__(16) short Vth[64][72], Vtl[64][72];
  __shared__ __align__(16) short Ph[64][72], Pl[64][72];

  short8 qh[2], ql[2];
  {
    const float* qp = q + ((size_t)(qt * 64 + w * 16 + l16) * H_ + h) * DH_;
    #pragma unroll
    for (int s = 0; s < 2; s++){
      float a8[8];
      *(float4*)&a8[0] = *(const float4*)(qp + lq * 8 + 32 * s);
      *(float4*)&a8[4] = *(const float4*)(qp + lq * 8 + 32 * s + 4);
      split8(a8, qh[s], ql[s]);
    }
  }

  float m_i[4], l_i[4];
  f32x4 acc[4];
  #pragma unroll
  for (int i = 0; i < 4; i++){ m_i[i] = -1e30f; l_i[i] = 0.f; acc[i] = (f32x4){0.f,0.f,0.f,0.f}; }

  const int kc = tid >> 2, kd = (tid & 3) * 16;
  const int vc0 = (tid & 15) * 4, vd0 = (tid >> 4) * 4;
  float kr[16], vr[16];

  {
    const float* kp = k + ((size_t)(0 + kc) * KV_ + kvh) * DH_ + kd;
    #pragma unroll
    for (int u = 0; u < 16; u += 4) *(float4*)&kr[u] = *(const float4*)(kp + u);
    #pragma unroll
    for (int cc = 0; cc < 4; cc++){
      const float* vp = v + ((size_t)(0 + vc0 + cc) * KV_ + kvh) * DH_ + vd0;
      *(float4*)&vr[cc * 4] = *(const float4*)vp;
    }
  }

  for (int kt = 0; kt <= qt; kt++){
    __syncthreads();
    {
      short8 h8, l8;
      split8(&kr[0], h8, l8);
      *(short8*)&Kh[kc][kd] = h8;     *(short8*)&Kl[kc][kd] = l8;
      split8(&kr[8], h8, l8);
      *(short8*)&Kh[kc][kd + 8] = h8; *(short8*)&Kl[kc][kd + 8] = l8;
      #pragma unroll
      for (int dd = 0; dd < 4; dd++){
        short4v hv, lv;
        #pragma unroll
        for (int cc = 0; cc < 4; cc++){
          float f = vr[cc * 4 + dd];
          short hb = f2bf(f);
          hv[cc] = hb;
          lv[cc] = f2bf(f - bf2f(hb));
        }
        *(short4v*)&Vth[vd0 + dd][vc0] = hv;
        *(short4v*)&Vtl[vd0 + dd][vc0] = lv;
      }
    }
    __syncthreads();
    if (kt < qt){
      const float* kp = k + ((size_t)((kt + 1) * 64 + kc) * KV_ + kvh) * DH_ + kd;
      #pragma unroll
      for (int u = 0; u < 16; u += 4) *(float4*)&kr[u] = *(const float4*)(kp + u);
      #pragma unroll
      for (int cc = 0; cc < 4; cc++){
        const float* vp = v + ((size_t)((kt + 1) * 64 + vc0 + cc) * KV_ + kvh) * DH_ + vd0;
        *(float4*)&vr[cc * 4] = *(const float4*)vp;
      }
    }

    f32x4 sa[4];
    #pragma unroll
    for (int ct = 0; ct < 4; ct++) sa[ct] = (f32x4){0.f,0.f,0.f,0.f};
    #pragma unroll
    for (int s = 0; s < 2; s++){
      #pragma unroll
      for (int ct = 0; ct < 4; ct++){
        short8 kh8 = *(const short8*)&Kh[ct * 16 + l16][lq * 8 + 32 * s];
        short8 kl8 = *(const short8*)&Kl[ct * 16 + l16][lq * 8 + 32 * s];
        sa[ct] = __builtin_amdgcn_mfma_f32_16x16x32_bf16(qh[s], kh8, sa[ct], 0, 0, 0);
        sa[ct] = __builtin_amdgcn_mfma_f32_16x16x32_bf16(qh[s], kl8, sa[ct], 0, 0, 0);
        sa[ct] = __builtin_amdgcn_mfma_f32_16x16x32_bf16(ql[s], kh8, sa[ct], 0, 0, 0);
      }
    }

    const bool diag = (kt == qt);
    #pragma unroll
    for (int ct = 0; ct < 4; ct++)
      #pragma unroll
      for (int i = 0; i < 4; i++){
        float sv = sa[ct][i] * 0.125f;
        if (diag && (ct * 16 + l16 > w * 16 + lq * 4 + i)) sv = -1e30f;
        sa[ct][i] = sv;
      }

    #pragma unroll
    for (int i = 0; i < 4; i++){
      float mx = fmaxf(fmaxf(sa[0][i], sa[1][i]), fmaxf(sa[2][i], sa[3][i]));
      #pragma unroll
      for (int o = 8; o; o >>= 1) mx = fmaxf(mx, __shfl_xor(mx, o));
      float mn = fmaxf(m_i[i], mx);
      float al = __expf(m_i[i] - mn);
      float ls = 0.f;
      #pragma unroll
      for (int ct = 0; ct < 4; ct++){
        float pv = __expf(sa[ct][i] - mn);
        sa[ct][i] = pv;
        ls += pv;
      }
      #pragma unroll
      for (int o = 8; o; o >>= 1) ls += __shfl_xor(ls, o);
      l_i[i] = l_i[i] * al + ls;
      m_i[i] = mn;
      #pragma unroll
      for (int dt = 0; dt < 4; dt++) acc[dt][i] *= al;
    }

    {
      int pr = w * 16 + lq * 4;
      #pragma unroll
      for (int i = 0; i < 4; i++)
        #pragma unroll
        for (int ct = 0; ct < 4; ct++){
          float pv = sa[ct][i];
          short hb = f2bf(pv);
          Ph[pr + i][ct * 16 + l16] = hb;
          Pl[pr + i][ct * 16 + l16] = f2bf(pv - bf2f(hb));
        }
    }
    __syncthreads();

    #pragma unroll
    for (int s = 0; s < 2; s++){
      short8 pah = *(const short8*)&Ph[w * 16 + l16][lq * 8 + 32 * s];
      short8 pal = *(const short8*)&Pl[w * 16 + l16][lq * 8 + 32 * s];
      #pragma unroll
      for (int dt = 0; dt < 4; dt++){
        short8 vh8 = *(const short8*)&Vth[dt * 16 + l16][lq * 8 + 32 * s];
        short8 vl8 = *(const short8*)&Vtl[dt * 16 + l16][lq * 8 + 32 * s];
        acc[dt] = __builtin_amdgcn_mfma_f32_16x16x32_bf16(pah, vh8, acc[dt], 0, 0, 0);
        acc[dt] = __builtin_amdgcn_mfma_f32_16x16x32_bf16(pah, vl8, acc[dt], 0, 0, 0);
        acc[dt] = __builtin_amdgcn_mfma_f32_16x16x32_bf16(pal, vh8, acc[dt], 0, 0, 0);
      }
    }
  }

  int orow = qt * 64 + w * 16 + lq * 4;
  #pragma unroll
  for (int i = 0; i < 4; i++){
    float inv = 1.f / l_i[i];
    #pragma unroll
    for (int dt = 0; dt < 4; dt++)
      out[(size_t)(orow + i) * (H_ * DH_) + h * DH_ + dt * 16 + l16] = acc[dt][i] * inv;
  }
}

// ======= split-bf16 MFMA GEMM core (vectored LDS staging + reg prefetch) =======
#define GEMM_LDS  __shared__ __align__(16) short Ah[64][40], Al[64][40], Bh[64][40], Bl[64][40]

// Core body macro: computes 64x64 tile at (row0,col0) of A[M,K']@B[K',N] where the
// k-range is [kbase, kbase+KH) of the full-K matrices (A row stride Kfull, B row stride N).
// Emits result into acc[4] (f32x4). Row guard: rows < Mlim valid.
#define GEMM_BODY(APTR, KFULL, KBASE, KH, BPTR, N_, MROW_OK)                                  \
  f32x4 acc[4] = {};                                                                          \
  {                                                                                           \
    int tid = threadIdx.x;                                                                    \
    int w_ = tid >> 6, lane = tid & 63, l16 = lane & 15, lq = lane >> 4;                      \
    int sm = tid & 63, sk = (tid >> 6) * 8;                                                   \
    (void)w_; (void)l16; (void)lq;                                                            \
    const float* Arow = (APTR) + (size_t)(KBASE) + sk;                                        \
    const float* Bcol = (BPTR) + (size_t)((KBASE) + sk) * (N_) + col0 + sm;                   \
    float a_reg[8], b_reg[8];                                                                 \
    if (MROW_OK){                                                                             \
      *(float4*)&a_reg[0] = *(const float4*)(Arow);                                           \
      *(float4*)&a_reg[4] = *(const float4*)(Arow + 4);                                       \
    } else {                                                                                  \
      _Pragma("unroll") for (int j = 0; j < 8; j++) a_reg[j] = 0.f;                           \
    }                                                                                         \
    _Pragma("unroll") for (int j = 0; j < 8; j++) b_reg[j] = Bcol[(size_t)j * (N_)];          \
    int nc = (KH) >> 5;                                                                       \
    for (int c = 0; c < nc; c++){                                                             \
      short8 h8, l8;                                                                          \
      split8(a_reg, h8, l8);                                                                  \
      *(short8*)&Ah[sm][sk] = h8;                                                             \
      *(short8*)&Al[sm][sk] = l8;                                                             \
      split8(b_reg, h8, l8);                                                                  \
      *(short8*)&Bh[sm][sk] = h8;                                                             \
      *(short8*)&Bl[sm][sk] = l8;                                                             \
      __syncthreads();                                                                        \
      if (c + 1 < nc){                                                                        \
        const float* An = Arow + (c + 1) * 32;                                                \
        if (MROW_OK){                                                                         \
          *(float4*)&a_reg[0] = *(const float4*)(An);                                         \
          *(float4*)&a_reg[4] = *(const float4*)(An + 4);                                     \
        }                                                                                     \
        const float* Bn = Bcol + (size_t)(c + 1) * 32 * (N_);                                 \
        _Pragma("unroll") for (int j = 0; j < 8; j++) b_reg[j] = Bn[(size_t)j * (N_)];        \
      }                                                                                       \
      short8 ah = *(const short8*)&Ah[w_ * 16 + l16][lq * 8];                                 \
      short8 al = *(const short8*)&Al[w_ * 16 + l16][lq * 8];                                 \
      _Pragma("unroll")                                                                       \
      for (int nt = 0; nt < 4; nt++){                                                         \
        short8 bh = *(const short8*)&Bh[nt * 16 + l16][lq * 8];                               \
        short8 bl = *(const short8*)&Bl[nt * 16 + l16][lq * 8];                               \
        acc[nt] = __builtin_amdgcn_mfma_f32_16x16x32_bf16(ah, bh, acc[nt], 0, 0, 0);          \
        acc[nt] = __builtin_amdgcn_mfma_f32_16x16x32_bf16(ah, bl, acc[nt], 0, 0, 0);          \
        acc[nt] = __builtin_amdgcn_mfma_f32_16x16x32_bf16(al, bh, acc[nt], 0, 0, 0);          \
      }                                                                                       \
      __syncthreads();                                                                        \
    }                                                                                         \
  }

// ---------------- generic: C[M,N] = A[M,K] @ B[K,N] ----------------
__global__ __launch_bounds__(256)
void k_mgemm(const float* __restrict__ A, const float* __restrict__ B,
             float* __restrict__ C, int M, int N, int K){
  GEMM_LDS;
  int row0 = blockIdx.y * 64, col0 = blockIdx.x * 64;
  int sm = threadIdx.x & 63;
  bool aok = (row0 + sm) < M;
  const float* Abase = A + (size_t)(row0 + sm) * K;
  GEMM_BODY(Abase, K, 0, K, B, N, aok);
  int w = threadIdx.x >> 6, lane = threadIdx.x & 63, l16 = lane & 15, lq = lane >> 4;
  #pragma unroll
  for (int nt = 0; nt < 4; nt++)
    #pragma unroll
    for (int i = 0; i < 4; i++){
      int r = row0 + w * 16 + lq * 4 + i;
      if (r < M) C[(size_t)r * N + col0 + nt * 16 + l16] = acc[nt][i];
    }
}

// ---------------- K-split x2 generic: partial C0/C1 = A@B halves ----------------
__global__ __launch_bounds__(256)
void k_mgemm_ks2(const float* __restrict__ A, const float* __restrict__ B,
                 float* __restrict__ C0, float* __restrict__ C1,
                 int M, int N, int K){
  GEMM_LDS;
  int row0 = blockIdx.y * 64, col0 = blockIdx.x * 64;
  int z = blockIdx.z, KH = K >> 1;
  int sm = threadIdx.x & 63;
  bool aok = (row0 + sm) < M;
  const float* Abase = A + (size_t)(row0 + sm) * K;
  GEMM_BODY(Abase, K, z * KH, KH, B, N, aok);
  float* C = z ? C1 : C0;
  int w = threadIdx.x >> 6, lane = threadIdx.x & 63, l16 = lane & 15, lq = lane >> 4;
  #pragma unroll
  for (int nt = 0; nt < 4; nt++)
    #pragma unroll
    for (int i = 0; i < 4; i++){
      int r = row0 + w * 16 + lq * 4 + i;
      if (r < M) C[(size_t)r * N + col0 + nt * 16 + l16] = acc[nt][i];
    }
}

// ---------------- fused QKV projection: col-block selects wq/wk/wv ----------------
__global__ __launch_bounds__(256)
void k_mgemm_qkv(const float* __restrict__ hn, const float* __restrict__ wq_l,
                 const float* __restrict__ wk_l, const float* __restrict__ wv_l,
                 float* __restrict__ qlin, float* __restrict__ kbuf,
                 float* __restrict__ vbuf){
  GEMM_LDS;
  int cb = blockIdx.x;
  const float* B; float* C; int N; int col0;
  if (cb < 16){ B = wq_l; C = qlin; N = H_ * DH_; col0 = cb * 64; }
  else if (cb < 20){ B = wk_l; C = kbuf; N = KV_ * DH_; col0 = (cb - 16) * 64; }
  else { B = wv_l; C = vbuf; N = KV_ * DH_; col0 = (cb - 20) * 64; }
  int row0 = blockIdx.y * 64;
  int sm = threadIdx.x & 63;
  const float* Abase = hn + (size_t)(row0 + sm) * D_;
  GEMM_BODY(Abase, D_, 0, D_, B, N, true);
  int w = threadIdx.x >> 6, lane = threadIdx.x & 63, l16 = lane & 15, lq = lane >> 4;
  #pragma unroll
  for (int nt = 0; nt < 4; nt++)
    #pragma unroll
    for (int i = 0; i < 4; i++){
      int r = row0 + w * 16 + lq * 4 + i;
      C[(size_t)r * N + col0 + nt * 16 + l16] = acc[nt][i];
    }
}

// ---------------- expert up, K-split x2: gathered A rows, partial outputs ----------
__global__ __launch_bounds__(256)
void k_mgemm_up(const float* __restrict__ hn, const float* __restrict__ egu_l,
                float* __restrict__ G0, float* __restrict__ G1,
                const int* __restrict__ counts, const int* __restrict__ offsets,
                const int* __restrict__ rowtok){
  const int z = blockIdx.z;
  const int e = z >> 1, s = z & 1;
  const int me = counts[e];
  const int row0 = blockIdx.y * 64;
  if (row0 >= me) return;
  const int off = offsets[e];
  const float* B = egu_l + (size_t)e * D_ * (2 * F_);
  const int N = 2 * F_, KH = D_ >> 1;
  GEMM_LDS;
  int col0 = blockIdx.x * 64;
  int sm = threadIdx.x & 63;
  bool aok = (row0 + sm) < me;
  int tok = aok ? rowtok[off + row0 + sm] : 0;
  const float* Abase = hn + (size_t)tok * D_;
  GEMM_BODY(Abase, D_, s * KH, KH, B, N, aok);
  float* G = s ? G1 : G0;
  int w = threadIdx.x >> 6, lane = threadIdx.x & 63, l16 = lane & 15, lq = lane >> 4;
  #pragma unroll
  for (int nt = 0; nt < 4; nt++)
    #pragma unroll
    for (int i = 0; i < 4; i++){
      int r = row0 + w * 16 + lq * 4 + i;
      if (r < me) G[(size_t)(off + r) * N + col0 + nt * 16 + l16] = acc[nt][i];
    }
}

// ---------------- expert down, K-split x2: + weighted scatter-add ----------------
__global__ __launch_bounds__(256)
void k_mgemm_dn(const float* __restrict__ he, const float* __restrict__ edn_l,
                float* __restrict__ routed, const int* __restrict__ counts,
                const int* __restrict__ offsets, const int* __restrict__ rowtok,
                const float* __restrict__ roww){
  const int z = blockIdx.z;
  const int e = z >> 1, s = z & 1;
  const int me = counts[e];
  const int row0 = blockIdx.y * 64;
  if (row0 >= me) return;
  const int off = offsets[e];
  const float* B = edn_l + (size_t)e * F_ * D_;
  const int N = D_, KH = F_ >> 1;
  GEMM_LDS;
  int col0 = blockIdx.x * 64;
  int sm = threadIdx.x & 63;
  bool aok = (row0 + sm) < me;
  const float* Abase = he + (size_t)(off + row0 + (aok ? sm : 0)) * F_;
  GEMM_BODY(Abase, F_, s * KH, KH, B, N, aok);
  int w = threadIdx.x >> 6, lane = threadIdx.x & 63, l16 = lane & 15, lq = lane >> 4;
  #pragma unroll
  for (int i = 0; i < 4; i++){
    int r = row0 + w * 16 + lq * 4 + i;
    if (r < me){
      int tok = rowtok[off + r];
      float wgt = roww[off + r];
      float* cp = routed + (size_t)tok * D_ + col0;
      #pragma unroll
      for (int nt = 0; nt < 4; nt++)
        atomicAdd(&cp[nt * 16 + l16], wgt * acc[nt][i]);
    }
  }
}

// ---------------- SiLU(gate)*up ----------------
__global__ void k_silumul(const float* __restrict__ g, float* __restrict__ out,
                          int width, int half){
  int idx = blockIdx.x * 256 + threadIdx.x;
  int r = idx / half, f = idx - r * half;
  float a = g[(size_t)r * width + f];
  float b = g[(size_t)r * width + half + f];
  out[idx] = a * b / (1.f + __expf(-a));
}

// ---- SiLU(gate)*up over summed K-split partials ----
__global__ void k_silumul2(const float* __restrict__ g0, const float* __restrict__ g1,
                           float* __restrict__ out, int width, int half){
  int idx = blockIdx.x * 256 + threadIdx.x;
  int r = idx / half, f = idx - r * half;
  size_t ia = (size_t)r * width + f, ib = (size_t)r * width + half + f;
  float a = g0[ia] + g1[ia];
  float b = g0[ib] + g1[ib];
  out[idx] = a * b / (1.f + __expf(-a));
}

// ---------------- shared-expert sigmoid gate ----------------
__global__ __launch_bounds__(256)
void k_gate(const float* __restrict__ hn, const float* __restrict__ sg,
            float* __restrict__ gate){
  int t = blockIdx.x, tid = threadIdx.x;
  const float* xr = hn + (size_t)t * D_;
  float s = 0.f;
  for (int d = tid; d < D_; d += 256) s += xr[d] * sg[d];
  #pragma unroll
  for (int o = 32; o; o >>= 1) s += __shfl_xor(s, o);
  __shared__ float red[4];
  if ((tid & 63) == 0) red[tid >> 6] = s;
  __syncthreads();
  if (tid == 0){
    float tot = red[0] + red[1] + red[2] + red[3];
    gate[t] = 1.f / (1.f + __expf(-tot));
  }
}

// ---------------- router: softmax + top-2 + renorm ----------------
__global__ __launch_bounds__(64)
void k_router(const float* __restrict__ hn, const float* __restrict__ rw,
              int* __restrict__ counts, int* __restrict__ top_e,
              float* __restrict__ top_w){
  int t = blockIdx.x;
  int lane = threadIdx.x;
  int e = lane & 7, c = lane >> 3;
  const float* xr = hn + (size_t)t * D_;
  float s = 0.f;
  for (int d = c * 128; d < c * 128 + 128; d++) s += xr[d] * rw[d * E_ + e];
  s += __shfl_down(s, 32);
  s += __shfl_down(s, 16);
  s += __shfl_down(s, 8);
  float v[8];
  #pragma unroll
  for (int qq = 0; qq < 8; qq++) v[qq] = __shfl(s, qq);
  if (lane == 0){
    float mx = v[0];
    #pragma unroll
    for (int qq = 1; qq < 8; qq++) mx = fmaxf(mx, v[qq]);
    float p[8];
    #pragma unroll
    for (int qq = 0; qq < 8; qq++) p[qq] = __expf(v[qq] - mx);
    int i0 = 0;
    #pragma unroll
    for (int qq = 1; qq < 8; qq++) if (p[qq] > p[i0]) i0 = qq;
    int i1 = (i0 == 0) ? 1 : 0;
    #pragma unroll
    for (int qq = 0; qq < 8; qq++) if (qq != i0 && p[qq] > p[i1]) i1 = qq;
    float w0 = p[i0], w1 = p[i1];
    float inv = 1.f / (w0 + w1);
    top_e[t * 2 + 0] = i0; top_w[t * 2 + 0] = w0 * inv;
    top_e[t * 2 + 1] = i1; top_w[t * 2 + 1] = w1 * inv;
    atomicAdd(&counts[i0], 1);
    atomicAdd(&counts[i1], 1);
  }
}

__global__ void k_prefix(const int* __restrict__ counts, int* __restrict__ offsets,
                         int* __restrict__ cursor){
  if (threadIdx.x == 0 && blockIdx.x == 0){
    int acc = 0;
    for (int e = 0; e < E_; e++){ offsets[e] = acc; cursor[e] = acc; acc += counts[e]; }
  }
}

__global__ void k_assign(const int* __restrict__ top_e, const float* __restrict__ top_w,
                         int* __restrict__ cursor, int* __restrict__ rowtok,
                         float* __restrict__ roww){
  int i = blockIdx.x * 256 + threadIdx.x;
  if (i >= T_ * TOPK_) return;
  int e = top_e[i];
  int slot = atomicAdd(&cursor[e], 1);
  rowtok[slot] = i >> 1;
  roww[slot] = top_w[i];
}

// ---- h = (p0 + p1) * gate[t]  (sdn K-split partials; experts scatter-add on top) ----
__global__ void k_prefill2(float* __restrict__ h, const float* __restrict__ p0,
                           const float* __restrict__ p1, const float* __restrict__ gate){
  int idx = blockIdx.x * 256 + threadIdx.x;
  h[idx] = (p0[idx] + p1[idx]) * gate[idx >> 10];
}

// ---------------- final: out = rms(res + h, final_ln), fp32 out ----------------
__global__ __launch_bounds__(256)
void k_final_rms(const float* __restrict__ resv, const float* __restrict__ hv,
                 const float* __restrict__ w, float* __restrict__ out){
  int t = blockIdx.x, tid = threadIdx.x;
  const float* xr = resv + (size_t)t * D_;
  const float* hr = hv + (size_t)t * D_;
  float ss = 0.f;
  for (int d = tid; d < D_; d += 256){ float v = xr[d] + hr[d]; ss += v * v; }
  #pragma unroll
  for (int o = 32; o; o >>= 1) ss += __shfl_xor(ss, o);
  __shared__ float red[4];
  if ((tid & 63) == 0) red[tid >> 6] = ss;
  __syncthreads();
  float r = rsqrtf((red[0] + red[1] + red[2] + red[3]) * (1.f / D_) + 1e-6f);
  float* orow = out + (size_t)t * D_;
  for (int d = tid; d < D_; d += 256) orow[d] = (xr[d] + hr[d]) * r * w[d];
}

extern "C" void kernel_launch(void* const* d_in, const int* in_sizes, int n_in,
                              void* d_out, int out_size, void* d_ws, size_t ws_size,
                              hipStream_t stream){
  (void)in_sizes; (void)n_in; (void)out_size; (void)ws_size;
  const int* ids = (const int*)d_in[0];
  const int* pos = (const int*)d_in[1];
  const float* emb = (const float*)d_in[2];
  const float* ln1 = (const float*)d_in[3];
  const float* wq  = (const float*)d_in[4];
  const float* wk  = (const float*)d_in[5];
  const float* wv  = (const float*)d_in[6];
  const float* wo  = (const float*)d_in[7];
  const float* qn  = (const float*)d_in[8];
  const float* kn  = (const float*)d_in[9];
  const float* ln2 = (const float*)d_in[10];
  const float* rw  = (const float*)d_in[11];
  const float* egu = (const float*)d_in[12];
  const float* edn = (const float*)d_in[13];
  const float* sgu = (const float*)d_in[14];
  const float* sdn = (const float*)d_in[15];
  const float* sg  = (const float*)d_in[16];
  const float* fln = (const float*)d_in[17];

  float* ws = (float*)d_ws;
  const size_t MB = (size_t)1 << 20;   // 1M floats per slot
  float* res    = ws;                  // [0,1)
  float* h      = ws + 1 * MB;         // [1,2)
  float* hn     = ws + 2 * MB;         // [2,3)
  float* qlin   = ws + 3 * MB;         // [3,4)   (attn phase)
  float* kbuf   = ws + 4 * MB;         // [4,5)   (attn phase)
  float* vbuf   = kbuf + T_ * KV_ * DH_;
  float* attnb  = ws + 5 * MB;         // [5,6)
  float* gu     = ws + 6 * MB;         // [6,10)
  float* sact   = ws + 10 * MB;        // [10,12)
  float* ps0    = ws + 12 * MB;        // [12,13)  sdn partial 0 (shexp slot)
  float* G0     = ws + 13 * MB;        // [13,15)  expert-up partial 0
  float* he     = ws + 15 * MB;        // [15,16)
  float* ps1    = ws + 16 * MB;        // [16,17)  sdn partial 1
  float* gate   = ws + 17 * MB;
  float* roww   = gate + 4096;
  float* top_w  = roww + 4096;
  int* counts   = (int*)(top_w + 4096);
  int* offsets  = counts + 8;
  int* cursor   = offsets + 8;
  int* top_e    = cursor + 8;
  int* rowtok   = top_e + 2048;
  // temporally-dead reuse (MoE phase): expert-up partial 1 over qlin+kv region
  float* G1     = ws + 3 * MB;         // [3,5)
  // temporally-dead reuse (attn phase): wo partials over qlin / kv regions
  float* pw0    = ws + 3 * MB;         // [3,4)
  float* pw1    = ws + 4 * MB;         // [4,5)

  const int NTD = T_ * D_ / 256;

  k_embed<<<NTD, 256, 0, stream>>>(ids, emb, h, res);

  for (int i = 0; i < L_; i++){
    // ---- attention ----
    k_fused_rms<<<T_, 256, 0, stream>>>(res, h, ln1 + (size_t)i * D_, hn);
    k_mgemm_qkv<<<dim3(24, 16), 256, 0, stream>>>(hn,
        wq + (size_t)i * D_ * (H_ * DH_), wk + (size_t)i * D_ * (KV_ * DH_),
        wv + (size_t)i * D_ * (KV_ * DH_), qlin, kbuf, vbuf);
    k_qknorm_rope<<<T_ * H_, 64, 0, stream>>>(qlin, qn + (size_t)i * DH_, pos, H_);
    k_qknorm_rope<<<T_ * KV_, 64, 0, stream>>>(kbuf, kn + (size_t)i * DH_, pos, KV_);
    k_fattn<<<dim3(H_, T_ / 64), 256, 0, stream>>>(qlin, kbuf, vbuf, attnb);
    k_mgemm_ks2<<<dim3(16, 16, 2), 256, 0, stream>>>(attnb, wo + (size_t)i * (H_ * DH_) * D_,
                                                     pw0, pw1, T_, D_, H_ * DH_);
    // ---- MoE MLP ----
    k_fused_rms2<<<T_, 256, 0, stream>>>(res, pw0, pw1, ln2 + (size_t)i * D_, hn);
    k_mgemm<<<dim3(64, 16), 256, 0, stream>>>(hn, sgu + (size_t)i * D_ * (2 * FS_), gu, T_, 2 * FS_, D_);
    k_silumul<<<T_ * FS_ / 256, 256, 0, stream>>>(gu, sact, 2 * FS_, FS_);
    k_mgemm_ks2<<<dim3(16, 16, 2), 256, 0, stream>>>(sact, sdn + (size_t)i * FS_ * D_,
                                                     ps0, ps1, T_, D_, FS_);
    k_gate<<<T_, 256, 0, stream>>>(hn, sg + (size_t)i * D_, gate);
    k_zero_i32<<<1, 64, 0, stream>>>(counts, 8);
    k_router<<<T_, 64, 0, stream>>>(hn, rw + (size_t)i * D_ * E_, counts, top_e, top_w);
    k_prefix<<<1, 1, 0, stream>>>(counts, offsets, cursor);
    k_assign<<<8, 256, 0, stream>>>(top_e, top_w, cursor, rowtok, roww);
    k_mgemm_up<<<dim3(16, 32, 16), 256, 0, stream>>>(hn, egu + (size_t)i * E_ * D_ * (2 * F_),
                                                     G0, G1, counts, offsets, rowtok);
    k_silumul2<<<T_ * TOPK_ * F_ / 256, 256, 0, stream>>>(G0, G1, he, 2 * F_, F_);
    k_prefill2<<<NTD, 256, 0, stream>>>(h, ps0, ps1, gate);
    k_mgemm_dn<<<dim3(16, 32, 16), 256, 0, stream>>>(he, edn + (size_t)i * E_ * F_ * D_,
                                                     h, counts, offsets, rowtok, roww);
  }

  k_final_rms<<<T_, 256, 0, stream>>>(res, h, fln, (float*)d_out);
}